// Round 11
// baseline (260.274 us; speedup 1.0000x reference)
//
#include <hip/hip_runtime.h>
#include <hip/hip_bf16.h>

#define D_MODEL 1024
#define NUM_HEADS 16
#define D_K 64
#define BATCH 2
#define SEQ 2048

typedef __attribute__((ext_vector_type(8))) short bf16x8;
typedef __attribute__((ext_vector_type(4))) float f32x4;

union P16 { int4 i4; ushort u[8]; };
union FU { float f; unsigned int u; };

__device__ __forceinline__ float bf2f(ushort u) {
    union { unsigned int i; float f; } c; c.i = ((unsigned int)u) << 16; return c.f;
}
__device__ __forceinline__ ushort f2bf(float f) {
    union { float f; unsigned int i; } c; c.f = f;
    unsigned int x = c.i;
    return (ushort)((x + 0x7fff + ((x >> 16) & 1)) >> 16);
}

// async 16B global->LDS (DMA; dest = wave-uniform base + lane*16)
typedef __attribute__((address_space(1))) void gv_t;
typedef __attribute__((address_space(3))) void lv_t;
__device__ __forceinline__ void gll16(const ushort* g, ushort* l) {
    __builtin_amdgcn_global_load_lds((gv_t*)g, (lv_t*)l, 16, 0, 0);
}

// Decide whether float inputs are fp32 (flag=1) or bf16 (flag=0) from x's bits.
__global__ void detect_f32(const ushort* __restrict__ x, int* __restrict__ flag) {
    int lane = threadIdx.x;               // 64 threads
    ushort u = x[2 * lane];
    int e = (u >> 7) & 0xFF;
    bool plausible = (e >= 100 && e <= 141);
    unsigned long long b = __ballot(plausible);
    if (lane == 0) flag[0] = (__popcll(b) < 32) ? 1 : 0;
}

// x fp32 -> bf16 (only when flag: bf16 inputs feed the GEMM directly)
__global__ void convert_x(const void* __restrict__ src, ushort* __restrict__ dst,
                          int n, const int* __restrict__ flag) {
    if (!*flag) return;
    int i = (blockIdx.x * 256 + threadIdx.x) * 8;
    if (i >= n) return;
    const float* f = (const float*)src + i;
    float4 a = *(const float4*)f, b = *(const float4*)(f + 4);
    P16 r;
    r.u[0] = f2bf(a.x); r.u[1] = f2bf(a.y); r.u[2] = f2bf(a.z); r.u[3] = f2bf(a.w);
    r.u[4] = f2bf(b.x); r.u[5] = f2bf(b.y); r.u[6] = f2bf(b.z); r.u[7] = f2bf(b.w);
    *(int4*)(dst + i) = r.i4;
}

// Both weight transposes in one kernel: WT[n][k] = W[k][n], bf16 out.
// blockIdx.x < 48 -> w_qkv (N=3072), else -> w_out (N=1024). K=1024 both.
__global__ void transpose_both(const void* __restrict__ Wq, const void* __restrict__ Wo,
                               ushort* __restrict__ WqT, ushort* __restrict__ WoT,
                               const int* __restrict__ flag) {
    __shared__ ushort t[64][72];
    const int tx = threadIdx.x;
    const int bx = blockIdx.x;
    const void* W; ushort* WT; int N, n0;
    if (bx < 48) { W = Wq; WT = WqT; N = 3 * D_MODEL; n0 = bx * 64; }
    else         { W = Wo; WT = WoT; N = D_MODEL;     n0 = (bx - 48) * 64; }
    const int k0 = blockIdx.y * 64, K = D_MODEL;
    const bool f32 = (*flag) != 0;
    #pragma unroll
    for (int p = 0; p < 16; ++p) {
        int r = p * 4 + (tx >> 6), c = tx & 63;
        float v = f32 ? ((const float*)W)[(size_t)(k0 + r) * N + n0 + c]
                      : bf2f(((const ushort*)W)[(size_t)(k0 + r) * N + n0 + c]);
        t[r][c] = f2bf(v);
    }
    __syncthreads();
    #pragma unroll
    for (int p = 0; p < 16; ++p) {
        int nn = p * 4 + (tx >> 6), kk = tx & 63;
        WT[(size_t)(n0 + nn) * K + k0 + kk] = t[kk][nn];
    }
}

// ---------------- m97-style GEMM ----------------
// MODE 1: A = flag ? Aconv : Araw(bf16); out = bf16 [row][N] (plain).
// MODE 0: A = Aconv (internal bf16); out dtype per flag, [row][N].
template<int MODE>
__global__ __launch_bounds__(256)
void gemm128(const void* __restrict__ Araw, const ushort* __restrict__ Aconv,
             const ushort* __restrict__ WT, const void* __restrict__ bias,
             void* __restrict__ out, int N, int K, const int* __restrict__ flag)
{
    __shared__ ushort As[128 * 32];
    __shared__ ushort Bs[128 * 32];

    const int f = *flag;
    const ushort* A = (MODE == 1) ? (f ? Aconv : (const ushort*)Araw) : Aconv;

    const int tid = threadIdx.x;
    const int w = tid >> 6, lane = tid & 63;
    const int ln = lane & 15, quad = lane >> 4;
    const int m0 = blockIdx.y * 128, n0 = blockIdx.x * 128;
    const int wm = (w >> 1) * 64, wn = (w & 1) * 64;

    const int s0 = w * 128 + lane, s1 = s0 + 64;
    const int ar0 = s0 >> 2, ak0 = ((s0 & 3) ^ ((ar0 >> 1) & 3)) * 8;
    const int ar1 = s1 >> 2, ak1 = ((s1 & 3) ^ ((ar1 >> 1) & 3)) * 8;
    const size_t aoff0 = (size_t)(m0 + ar0) * K + ak0;
    const size_t aoff1 = (size_t)(m0 + ar1) * K + ak1;
    const size_t boff0 = (size_t)(n0 + ar0) * K + ak0;
    const size_t boff1 = (size_t)(n0 + ar1) * K + ak1;
    ushort* asd0 = As + (size_t)(w * 2)     * 512;
    ushort* asd1 = As + (size_t)(w * 2 + 1) * 512;
    ushort* bsd0 = Bs + (size_t)(w * 2)     * 512;
    ushort* bsd1 = Bs + (size_t)(w * 2 + 1) * 512;

    const int physc = (quad ^ ((ln >> 1) & 3)) * 8;

    f32x4 acc[4][4] = {};

    for (int k0c = 0; k0c < K; k0c += 32) {
        __syncthreads();
        gll16(A  + aoff0 + k0c, asd0);
        gll16(A  + aoff1 + k0c, asd1);
        gll16(WT + boff0 + k0c, bsd0);
        gll16(WT + boff1 + k0c, bsd1);
        __syncthreads();

        bf16x8 af[4], bf[4];
        #pragma unroll
        for (int t = 0; t < 4; ++t) {
            af[t] = *(const bf16x8*)(As + (wm + t * 16 + ln) * 32 + physc);
            bf[t] = *(const bf16x8*)(Bs + (wn + t * 16 + ln) * 32 + physc);
        }
        #pragma unroll
        for (int mi = 0; mi < 4; ++mi)
            #pragma unroll
            for (int ni = 0; ni < 4; ++ni)
                acc[mi][ni] = __builtin_amdgcn_mfma_f32_16x16x32_bf16(
                    af[mi], bf[ni], acc[mi][ni], 0, 0, 0);
    }

    #pragma unroll
    for (int mi = 0; mi < 4; ++mi) {
        #pragma unroll
        for (int ni = 0; ni < 4; ++ni) {
            int col = n0 + wn + ni * 16 + ln;
            float bb = f ? ((const float*)bias)[col] : bf2f(((const ushort*)bias)[col]);
            #pragma unroll
            for (int r = 0; r < 4; ++r) {
                int row = m0 + wm + mi * 16 + quad * 4 + r;
                float v = acc[mi][ni][r] + bb;
                if (MODE == 0 && f) ((float*)out)[(size_t)row * N + col] = v;
                else                ((ushort*)out)[(size_t)row * N + col] = f2bf(v);
            }
        }
    }
}

// ---------------- MFMA flash attention v6 ----------------
// Same verified v5 body (fused q-tile pairs, one kv sweep, XCD swizzle via
// blockIdx.x=bh, ones-MFMA row-sum, no running max, truncating P pack), but
// Q/K/V read directly from the GEMM's natural [4096][3072] layout:
// elem(s, which, c) = qkv[(b*SEQ+s)*3072 + which*1024 + hh*64 + c].
// This removes the GEMM scatter epilogue (write-amplification fix).
__global__ __launch_bounds__(128)
void flash_attn6(const ushort* __restrict__ qkv, ushort* __restrict__ attn)
{
    __shared__ ushort Ks[64][72];
    __shared__ ushort Vs[64][72];
    __shared__ ushort QPs[64][72];   // rows 0..31 = qtA tile, 32..63 = qtB tile

    const int tid  = threadIdx.x;
    const int wave = tid >> 6, lane = tid & 63;
    const int ln   = lane & 15, quad = lane >> 4;
    const int bh   = blockIdx.x;    // x = bh -> all blocks of a bh on XCD bh%8
    const int xx   = blockIdx.y;
    const int b    = bh >> 4, hh = bh & (NUM_HEADS - 1);
    const int W3   = 3 * D_MODEL;
    const size_t hbase = (size_t)b * SEQ * W3 + hh * D_K;   // + s*W3 + which*1024

    const int q0A = 32 * (63 - xx), q0B = 32 * xx;
    const int ntA = ((63 - xx) >> 1) + 1, ntB = (xx >> 1) + 1;   // ntB <= ntA

    const int srow = tid >> 1, scol = (tid & 1) * 32;   // K/Q staging ownership
    const int vp = tid & 31, vg = (tid >> 5) * 8;       // V staging ownership

    // stage both Q tiles, scaled by 0.125*log2(e) (log2-domain scores)
    {
        const int rglob = (srow < 32) ? (q0A + srow) : (q0B + srow - 32);
        const ushort* src = qkv + hbase + (size_t)rglob * W3 + scol;
        #pragma unroll
        for (int h = 0; h < 4; ++h) {
            P16 v; v.i4 = *(const int4*)(src + h * 8);
            #pragma unroll
            for (int e = 0; e < 8; ++e) v.u[e] = f2bf(bf2f(v.u[e]) * 0.18033688011f);
            *(int4*)(&QPs[srow][scol + h * 8]) = v.i4;
        }
    }
    __syncthreads();
    bf16x8 qf[2][2];
    #pragma unroll
    for (int mt = 0; mt < 2; ++mt)
        #pragma unroll
        for (int s = 0; s < 2; ++s)
            qf[mt][s] = *(const bf16x8*)(&QPs[mt * 32 + wave * 16 + ln][s * 32 + quad * 8]);
    // P rows this wave writes = rows whose Q-frags it read -> in-order DS, no barrier.

    f32x4 acc_o[2][4] = {};
    f32x4 acc_l[2] = {};

    bf16x8 ones8;
    #pragma unroll
    for (int e = 0; e < 8; ++e) ones8[e] = (short)0x3F80;   // bf16 1.0

    const ushort* Kbase = qkv + hbase + D_MODEL;
    const ushort* Vbase = qkv + hbase + 2 * D_MODEL;

    int4 kreg[4], vreg[2][2];
    // preload kv tile 0
    {
        const ushort* ksrc = Kbase + (size_t)srow * W3 + scol;
        kreg[0] = *(const int4*)(ksrc);
        kreg[1] = *(const int4*)(ksrc + 8);
        kreg[2] = *(const int4*)(ksrc + 16);
        kreg[3] = *(const int4*)(ksrc + 24);
        #pragma unroll
        for (int h = 0; h < 2; ++h) {
            const int dk0 = vg + h * 32;
            vreg[h][0] = *(const int4*)(Vbase + (size_t)(2 * vp)     * W3 + dk0);
            vreg[h][1] = *(const int4*)(Vbase + (size_t)(2 * vp + 1) * W3 + dk0);
        }
    }

    for (int jt = 0; jt < ntA; ++jt) {
        const int j0 = jt * 64;
        const bool doB = (jt < ntB);
        __syncthreads();   // prior iteration's Ks/Vs reads done

        // write prefetched regs -> LDS
        *(int4*)(&Ks[srow][scol])      = kreg[0];
        *(int4*)(&Ks[srow][scol + 8])  = kreg[1];
        *(int4*)(&Ks[srow][scol + 16]) = kreg[2];
        *(int4*)(&Ks[srow][scol + 24]) = kreg[3];
        #pragma unroll
        for (int h = 0; h < 2; ++h) {
            const int dk0 = vg + h * 32;
            P16 v0, v1; v0.i4 = vreg[h][0]; v1.i4 = vreg[h][1];
            #pragma unroll
            for (int e = 0; e < 8; ++e) {
                unsigned int pack = (unsigned int)v0.u[e] | ((unsigned int)v1.u[e] << 16);
                *(unsigned int*)(&Vs[dk0 + e][2 * vp]) = pack;
            }
        }
        __syncthreads();

        // issue next tile's global loads (overlap with compute below)
        if (jt + 1 < ntA) {
            const int jn = j0 + 64;
            const ushort* ksrc = Kbase + (size_t)(jn + srow) * W3 + scol;
            kreg[0] = *(const int4*)(ksrc);
            kreg[1] = *(const int4*)(ksrc + 8);
            kreg[2] = *(const int4*)(ksrc + 16);
            kreg[3] = *(const int4*)(ksrc + 24);
            #pragma unroll
            for (int h = 0; h < 2; ++h) {
                const int dk0 = vg + h * 32;
                vreg[h][0] = *(const int4*)(Vbase + (size_t)(jn + 2 * vp)     * W3 + dk0);
                vreg[h][1] = *(const int4*)(Vbase + (size_t)(jn + 2 * vp + 1) * W3 + dk0);
            }
        }

        // S = Q K^T (K-frags read once, shared across both q-tiles)
        f32x4 sa[2][4];
        #pragma unroll
        for (int t = 0; t < 4; ++t) {
            bf16x8 k0 = *(const bf16x8*)(&Ks[t * 16 + ln][quad * 8]);
            bf16x8 k1 = *(const bf16x8*)(&Ks[t * 16 + ln][32 + quad * 8]);
            {
                f32x4 z = {};
                z = __builtin_amdgcn_mfma_f32_16x16x32_bf16(qf[0][0], k0, z, 0, 0, 0);
                z = __builtin_amdgcn_mfma_f32_16x16x32_bf16(qf[0][1], k1, z, 0, 0, 0);
                sa[0][t] = z;
            }
            if (doB) {
                f32x4 z = {};
                z = __builtin_amdgcn_mfma_f32_16x16x32_bf16(qf[1][0], k0, z, 0, 0, 0);
                z = __builtin_amdgcn_mfma_f32_16x16x32_bf16(qf[1][1], k1, z, 0, 0, 0);
                sa[1][t] = z;
            }
        }

        // causal mask on each tile's own diagonal kv-tile (exp2(-1e30)=0)
        if (jt == ntA - 1) {
            const int rowb = q0A + wave * 16 + quad * 4;
            #pragma unroll
            for (int t = 0; t < 4; ++t)
                #pragma unroll
                for (int r = 0; r < 4; ++r)
                    if (j0 + t * 16 + ln > rowb + r) sa[0][t][r] = -1e30f;
        }
        if (doB && jt == ntB - 1) {
            const int rowb = q0B + wave * 16 + quad * 4;
            #pragma unroll
            for (int t = 0; t < 4; ++t)
                #pragma unroll
                for (int r = 0; r < 4; ++r)
                    if (j0 + t * 16 + ln > rowb + r) sa[1][t][r] = -1e30f;
        }

        // P = exp2(s), truncating bf16 pack, straight to LDS (physcol = col ^ quad*8)
        const int lnx = ln ^ ((quad & 1) * 8);
        #pragma unroll
        for (int mt = 0; mt < 2; ++mt) {
            if (mt && !doB) break;
            #pragma unroll
            for (int r = 0; r < 4; ++r) {
                const int prow = mt * 32 + wave * 16 + quad * 4 + r;
                #pragma unroll
                for (int t = 0; t < 4; ++t) {
                    FU cc; cc.f = exp2f(sa[mt][t][r]);
                    QPs[prow][((t ^ (quad >> 1)) * 16) + lnx] = (ushort)(cc.u >> 16);
                }
            }
        }

        // O += P @ V ; l += P @ 1. pf unswizzle: phys = quad ^ ((ln>>2)&3)
        #pragma unroll
        for (int s = 0; s < 2; ++s) {
            const int pcol = s * 32 + ((quad ^ ((ln >> 2) & 3)) * 8);
            bf16x8 pf0 = *(const bf16x8*)(&QPs[wave * 16 + ln][pcol]);
            bf16x8 pf1;
            if (doB) pf1 = *(const bf16x8*)(&QPs[32 + wave * 16 + ln][pcol]);
            #pragma unroll
            for (int t = 0; t < 4; ++t) {
                bf16x8 vf = *(const bf16x8*)(&Vs[t * 16 + ln][s * 32 + quad * 8]);
                acc_o[0][t] = __builtin_amdgcn_mfma_f32_16x16x32_bf16(pf0, vf, acc_o[0][t], 0, 0, 0);
                if (doB)
                    acc_o[1][t] = __builtin_amdgcn_mfma_f32_16x16x32_bf16(pf1, vf, acc_o[1][t], 0, 0, 0);
            }
            acc_l[0] = __builtin_amdgcn_mfma_f32_16x16x32_bf16(pf0, ones8, acc_l[0], 0, 0, 0);
            if (doB)
                acc_l[1] = __builtin_amdgcn_mfma_f32_16x16x32_bf16(pf1, ones8, acc_l[1], 0, 0, 0);
        }
    }

    // epilogue: normalize, write [B,S,H*64+dk]
    #pragma unroll
    for (int mt = 0; mt < 2; ++mt) {
        const int q0 = mt ? q0B : q0A;
        #pragma unroll
        for (int r = 0; r < 4; ++r) {
            float inv = 1.0f / acc_l[mt][r];
            int i = q0 + wave * 16 + quad * 4 + r;
            size_t rowoff = ((size_t)(b * SEQ + i)) * D_MODEL + hh * D_K;
            #pragma unroll
            for (int t = 0; t < 4; ++t)
                attn[rowoff + t * 16 + ln] = f2bf(acc_o[mt][t][r] * inv);
        }
    }
}

extern "C" void kernel_launch(void* const* d_in, const int* in_sizes, int n_in,
                              void* d_out, int out_size, void* d_ws, size_t ws_size,
                              hipStream_t stream)
{
    const void* x     = d_in[0];
    // d_in[1] = int32 tril mask -- causal handled analytically
    const void* w_qkv = d_in[2];
    const void* b_qkv = d_in[3];
    const void* w_out = d_in[4];
    const void* b_out = d_in[5];

    char* ws = (char*)d_ws;
    int*    flag   = (int*)ws;                  size_t off = 256;
    ushort* WqkvT  = (ushort*)(ws + off);       off += (size_t)3 * D_MODEL * D_MODEL * 2;
    ushort* WoutT  = (ushort*)(ws + off);       off += (size_t)D_MODEL * D_MODEL * 2;
    ushort* qkv_ws = (ushort*)(ws + off);       off += (size_t)BATCH * SEQ * 3 * D_MODEL * 2;
    ushort* xb     = (ushort*)(ws + off);       // aliases attn_ws: xb dead after QKV gemm
    ushort* attn_ws = xb;

    const int M = BATCH * SEQ;          // 4096

    detect_f32<<<1, 64, 0, stream>>>((const ushort*)x, flag);

    const int nx = M * D_MODEL;
    convert_x<<<nx / 8 / 256, 256, 0, stream>>>(x, xb, nx, flag);
    transpose_both<<<dim3(64, 16), 256, 0, stream>>>(w_qkv, w_out, WqkvT, WoutT, flag);

    gemm128<1><<<dim3(3 * D_MODEL / 128, M / 128), 256, 0, stream>>>(
        x, xb, WqkvT, b_qkv, qkv_ws, 3 * D_MODEL, D_MODEL, flag);

    dim3 ga(BATCH * NUM_HEADS, 32);   // x = bh (XCD locality), y = pair index
    flash_attn6<<<ga, 128, 0, stream>>>(qkv_ws, attn_ws);

    gemm128<0><<<dim3(D_MODEL / 128, M / 128), 256, 0, stream>>>(
        attn_ws, attn_ws, WoutT, b_out, d_out, D_MODEL, D_MODEL, flag);
}

// Round 12
// 226.902 us; speedup vs baseline: 1.1471x; 1.1471x over previous
//
#include <hip/hip_runtime.h>
#include <hip/hip_bf16.h>

#define D_MODEL 1024
#define NUM_HEADS 16
#define D_K 64
#define BATCH 2
#define SEQ 2048

typedef __attribute__((ext_vector_type(8))) short bf16x8;
typedef __attribute__((ext_vector_type(4))) float f32x4;

union P16 { int4 i4; ushort u[8]; };
union FU { float f; unsigned int u; };

__device__ __forceinline__ float bf2f(ushort u) {
    union { unsigned int i; float f; } c; c.i = ((unsigned int)u) << 16; return c.f;
}
__device__ __forceinline__ ushort f2bf(float f) {
    union { float f; unsigned int i; } c; c.f = f;
    unsigned int x = c.i;
    return (ushort)((x + 0x7fff + ((x >> 16) & 1)) >> 16);
}

// async 16B global->LDS (DMA; dest = wave-uniform base + lane*16)
typedef __attribute__((address_space(1))) void gv_t;
typedef __attribute__((address_space(3))) void lv_t;
__device__ __forceinline__ void gll16(const ushort* g, ushort* l) {
    __builtin_amdgcn_global_load_lds((gv_t*)g, (lv_t*)l, 16, 0, 0);
}

// per-wave inline dtype detect (every wave reads the same 64 values -> uniform)
__device__ __forceinline__ bool wave_detect_f32(const ushort* x) {
    ushort u = x[2 * (threadIdx.x & 63)];
    int e = (u >> 7) & 0xFF;
    unsigned long long bl = __ballot(e >= 100 && e <= 141);
    return __popcll(bl) < 32;
}

// ---------------- fused prep: detect + convert_x + both weight transposes ----------------
// grid.x = 3072 blocks x 256 thr:
//   bx < 1024 : transpose tile (nb = bx&63 -> which/ n0, kb = bx>>6 -> k0)
//   bx >= 1024: convert x chunk (only when fp32)
// block 0 thread 0 also publishes flag for the gemm/flash kernels.
__global__ __launch_bounds__(256)
void prep_all(const ushort* __restrict__ x, const void* __restrict__ Wq,
              const void* __restrict__ Wo, ushort* __restrict__ xb,
              ushort* __restrict__ WqT, ushort* __restrict__ WoT,
              int* __restrict__ flag)
{
    const bool f32 = wave_detect_f32(x);
    const int bx = blockIdx.x, tx = threadIdx.x;
    if (bx == 0 && tx == 0) flag[0] = f32 ? 1 : 0;

    if (bx >= 1024) {               // convert x -> bf16 (fp32 inputs only)
        if (!f32) return;
        int i = ((bx - 1024) * 256 + tx) * 8;
        const float* f = (const float*)x + i;
        float4 a = *(const float4*)f, b = *(const float4*)(f + 4);
        P16 r;
        r.u[0] = f2bf(a.x); r.u[1] = f2bf(a.y); r.u[2] = f2bf(a.z); r.u[3] = f2bf(a.w);
        r.u[4] = f2bf(b.x); r.u[5] = f2bf(b.y); r.u[6] = f2bf(b.z); r.u[7] = f2bf(b.w);
        *(int4*)(xb + i) = r.i4;
        return;
    }

    __shared__ ushort t[64][72];
    const int nb = bx & 63, kb = bx >> 6;
    const void* W; ushort* WT; int N, n0;
    if (nb < 48) { W = Wq; WT = WqT; N = 3 * D_MODEL; n0 = nb * 64; }
    else         { W = Wo; WT = WoT; N = D_MODEL;     n0 = (nb - 48) * 64; }
    const int k0 = kb * 64, K = D_MODEL;
    #pragma unroll
    for (int p = 0; p < 16; ++p) {
        int r = p * 4 + (tx >> 6), c = tx & 63;
        float v = f32 ? ((const float*)W)[(size_t)(k0 + r) * N + n0 + c]
                      : bf2f(((const ushort*)W)[(size_t)(k0 + r) * N + n0 + c]);
        t[r][c] = f2bf(v);
    }
    __syncthreads();
    #pragma unroll
    for (int p = 0; p < 16; ++p) {
        int nn = p * 4 + (tx >> 6), kk = tx & 63;
        WT[(size_t)(n0 + nn) * K + k0 + kk] = t[kk][nn];
    }
}

// ---------------- m97-style GEMM (unchanged, verified) ----------------
// MODE 1: A = flag ? Aconv : Araw(bf16); out = bf16 [row][N].
// MODE 0: A = Aconv (internal bf16); out dtype per flag, [row][N].
template<int MODE>
__global__ __launch_bounds__(256)
void gemm128(const void* __restrict__ Araw, const ushort* __restrict__ Aconv,
             const ushort* __restrict__ WT, const void* __restrict__ bias,
             void* __restrict__ out, int N, int K, const int* __restrict__ flag)
{
    __shared__ ushort As[128 * 32];
    __shared__ ushort Bs[128 * 32];

    const int f = *flag;
    const ushort* A = (MODE == 1) ? (f ? Aconv : (const ushort*)Araw) : Aconv;

    const int tid = threadIdx.x;
    const int w = tid >> 6, lane = tid & 63;
    const int ln = lane & 15, quad = lane >> 4;
    const int m0 = blockIdx.y * 128, n0 = blockIdx.x * 128;
    const int wm = (w >> 1) * 64, wn = (w & 1) * 64;

    const int s0 = w * 128 + lane, s1 = s0 + 64;
    const int ar0 = s0 >> 2, ak0 = ((s0 & 3) ^ ((ar0 >> 1) & 3)) * 8;
    const int ar1 = s1 >> 2, ak1 = ((s1 & 3) ^ ((ar1 >> 1) & 3)) * 8;
    const size_t aoff0 = (size_t)(m0 + ar0) * K + ak0;
    const size_t aoff1 = (size_t)(m0 + ar1) * K + ak1;
    const size_t boff0 = (size_t)(n0 + ar0) * K + ak0;
    const size_t boff1 = (size_t)(n0 + ar1) * K + ak1;
    ushort* asd0 = As + (size_t)(w * 2)     * 512;
    ushort* asd1 = As + (size_t)(w * 2 + 1) * 512;
    ushort* bsd0 = Bs + (size_t)(w * 2)     * 512;
    ushort* bsd1 = Bs + (size_t)(w * 2 + 1) * 512;

    const int physc = (quad ^ ((ln >> 1) & 3)) * 8;

    f32x4 acc[4][4] = {};

    for (int k0c = 0; k0c < K; k0c += 32) {
        __syncthreads();
        gll16(A  + aoff0 + k0c, asd0);
        gll16(A  + aoff1 + k0c, asd1);
        gll16(WT + boff0 + k0c, bsd0);
        gll16(WT + boff1 + k0c, bsd1);
        __syncthreads();

        bf16x8 af[4], bf[4];
        #pragma unroll
        for (int t = 0; t < 4; ++t) {
            af[t] = *(const bf16x8*)(As + (wm + t * 16 + ln) * 32 + physc);
            bf[t] = *(const bf16x8*)(Bs + (wn + t * 16 + ln) * 32 + physc);
        }
        #pragma unroll
        for (int mi = 0; mi < 4; ++mi)
            #pragma unroll
            for (int ni = 0; ni < 4; ++ni)
                acc[mi][ni] = __builtin_amdgcn_mfma_f32_16x16x32_bf16(
                    af[mi], bf[ni], acc[mi][ni], 0, 0, 0);
    }

    #pragma unroll
    for (int mi = 0; mi < 4; ++mi) {
        #pragma unroll
        for (int ni = 0; ni < 4; ++ni) {
            int col = n0 + wn + ni * 16 + ln;
            float bb = f ? ((const float*)bias)[col] : bf2f(((const ushort*)bias)[col]);
            #pragma unroll
            for (int r = 0; r < 4; ++r) {
                int row = m0 + wm + mi * 16 + quad * 4 + r;
                float v = acc[mi][ni][r] + bb;
                if (MODE == 0 && f) ((float*)out)[(size_t)row * N + col] = v;
                else                ((ushort*)out)[(size_t)row * N + col] = f2bf(v);
            }
        }
    }
}

// ---------------- MFMA flash attention v7: 4-wave blocks, 2 fused q-pairs ----------------
// Pairs xx=2k and xx=2k+1 have IDENTICAL (ntA,ntB)=(32-k,k+1): waves {0,1}
// handle xx=2k, waves {2,3} handle xx=2k+1, all marching one shared kv sweep.
// K/V staged once per tile for 4 waves (staging cost per wave halved vs v6).
// ky->k map (ky<8?ky:23-ky) makes CU-resident block pairs sum to 49 iters
// under round-robin dispatch (perf heuristic only). Q/K/V read from the
// [4096][3072] qkv layout. Softmax: exp2, no bias, no running max; l via
// ones-MFMA; P packed by truncation (all verified rounds 7-11).
__global__ __launch_bounds__(256)
void flash_attn7(const ushort* __restrict__ qkv, ushort* __restrict__ attn)
{
    __shared__ ushort Ks[64][72];
    __shared__ ushort Vs[64][72];
    __shared__ ushort QPs[128][72];  // [pg*64 + mt*32 + local]

    const int tid  = threadIdx.x;          // 256 thr, 4 waves
    const int wave = tid >> 6, lane = tid & 63;
    const int ln   = lane & 15, quad = lane >> 4;
    const int pg   = wave >> 1, ww = wave & 1;
    const int bh   = blockIdx.x;    // all blocks of a bh land on XCD bh%8
    const int ky   = blockIdx.y;
    const int k    = (ky < 8) ? ky : 23 - ky;
    const int xx   = 2 * k + pg;
    const int b    = bh >> 4, hh = bh & (NUM_HEADS - 1);
    const int W3   = 3 * D_MODEL;
    const size_t hbase = (size_t)b * SEQ * W3 + hh * D_K;

    const int q0A = 32 * (63 - xx), q0B = 32 * xx;
    const int ntA = 32 - k, ntB = k + 1;     // identical for both pg

    // staging ownership
    const int qrr = tid >> 1, qcol = (tid & 1) * 32;       // Q: 128 rows x 64
    const int ksr = tid >> 2, ksc = (tid & 3) * 16;        // K: 64 rows, 2 int4
    const int vp  = tid & 31, vg = (tid >> 5) * 8;         // V: 8 b32 each

    // stage both pairs' Q tiles (128 rows), scaled by 0.125*log2(e)
    {
        const int qpg = qrr >> 6, qmt = (qrr >> 5) & 1, ql = qrr & 31;
        const int qxx = 2 * k + qpg;
        const int grow = qmt ? (32 * qxx + ql) : (32 * (63 - qxx) + ql);
        const ushort* src = qkv + hbase + (size_t)grow * W3 + qcol;
        #pragma unroll
        for (int h = 0; h < 4; ++h) {
            P16 v; v.i4 = *(const int4*)(src + h * 8);
            #pragma unroll
            for (int e = 0; e < 8; ++e) v.u[e] = f2bf(bf2f(v.u[e]) * 0.18033688011f);
            *(int4*)(&QPs[qrr][qcol + h * 8]) = v.i4;
        }
    }
    __syncthreads();
    bf16x8 qf[2][2];
    #pragma unroll
    for (int mt = 0; mt < 2; ++mt)
        #pragma unroll
        for (int s = 0; s < 2; ++s)
            qf[mt][s] = *(const bf16x8*)(&QPs[pg * 64 + mt * 32 + ww * 16 + ln][s * 32 + quad * 8]);
    // P rows this wave writes = rows whose Q-frags it read -> per-wave in-order DS.

    f32x4 acc_o[2][4] = {};
    f32x4 acc_l[2] = {};

    bf16x8 ones8;
    #pragma unroll
    for (int e = 0; e < 8; ++e) ones8[e] = (short)0x3F80;   // bf16 1.0

    const ushort* Kbase = qkv + hbase + D_MODEL;
    const ushort* Vbase = qkv + hbase + 2 * D_MODEL;

    int4 kreg[2], vreg[2];
    {
        const ushort* ksrc = Kbase + (size_t)ksr * W3 + ksc;
        kreg[0] = *(const int4*)(ksrc);
        kreg[1] = *(const int4*)(ksrc + 8);
        vreg[0] = *(const int4*)(Vbase + (size_t)(2 * vp)     * W3 + vg);
        vreg[1] = *(const int4*)(Vbase + (size_t)(2 * vp + 1) * W3 + vg);
    }

    for (int jt = 0; jt < ntA; ++jt) {
        const int j0 = jt * 64;
        const bool doB = (jt < ntB);
        __syncthreads();   // prior iteration's Ks/Vs reads done

        // write prefetched regs -> LDS
        *(int4*)(&Ks[ksr][ksc])     = kreg[0];
        *(int4*)(&Ks[ksr][ksc + 8]) = kreg[1];
        {
            P16 v0, v1; v0.i4 = vreg[0]; v1.i4 = vreg[1];
            #pragma unroll
            for (int e = 0; e < 8; ++e) {
                unsigned int pack = (unsigned int)v0.u[e] | ((unsigned int)v1.u[e] << 16);
                *(unsigned int*)(&Vs[vg + e][2 * vp]) = pack;
            }
        }
        __syncthreads();

        // issue next tile's global loads (overlap with compute)
        if (jt + 1 < ntA) {
            const int jn = j0 + 64;
            const ushort* ksrc = Kbase + (size_t)(jn + ksr) * W3 + ksc;
            kreg[0] = *(const int4*)(ksrc);
            kreg[1] = *(const int4*)(ksrc + 8);
            vreg[0] = *(const int4*)(Vbase + (size_t)(jn + 2 * vp)     * W3 + vg);
            vreg[1] = *(const int4*)(Vbase + (size_t)(jn + 2 * vp + 1) * W3 + vg);
        }

        // S = Q K^T (K-frags shared across this wave's two q-tiles)
        f32x4 sa[2][4];
        #pragma unroll
        for (int t = 0; t < 4; ++t) {
            bf16x8 k0 = *(const bf16x8*)(&Ks[t * 16 + ln][quad * 8]);
            bf16x8 k1 = *(const bf16x8*)(&Ks[t * 16 + ln][32 + quad * 8]);
            {
                f32x4 z = {};
                z = __builtin_amdgcn_mfma_f32_16x16x32_bf16(qf[0][0], k0, z, 0, 0, 0);
                z = __builtin_amdgcn_mfma_f32_16x16x32_bf16(qf[0][1], k1, z, 0, 0, 0);
                sa[0][t] = z;
            }
            if (doB) {
                f32x4 z = {};
                z = __builtin_amdgcn_mfma_f32_16x16x32_bf16(qf[1][0], k0, z, 0, 0, 0);
                z = __builtin_amdgcn_mfma_f32_16x16x32_bf16(qf[1][1], k1, z, 0, 0, 0);
                sa[1][t] = z;
            }
        }

        // causal mask (diag tiles: jt==ntA-1 for A rows, jt==ntB-1 for B rows)
        if (jt == ntA - 1) {
            const int rowb = q0A + ww * 16 + quad * 4;
            #pragma unroll
            for (int t = 0; t < 4; ++t)
                #pragma unroll
                for (int r = 0; r < 4; ++r)
                    if (j0 + t * 16 + ln > rowb + r) sa[0][t][r] = -1e30f;
        }
        if (doB && jt == ntB - 1) {
            const int rowb = q0B + ww * 16 + quad * 4;
            #pragma unroll
            for (int t = 0; t < 4; ++t)
                #pragma unroll
                for (int r = 0; r < 4; ++r)
                    if (j0 + t * 16 + ln > rowb + r) sa[1][t][r] = -1e30f;
        }

        // P = exp2(s), truncating bf16 pack, to QPs (physcol = col ^ quad*8)
        const int lnx = ln ^ ((quad & 1) * 8);
        #pragma unroll
        for (int mt = 0; mt < 2; ++mt) {
            if (mt && !doB) break;
            #pragma unroll
            for (int r = 0; r < 4; ++r) {
                const int prow = pg * 64 + mt * 32 + ww * 16 + quad * 4 + r;
                #pragma unroll
                for (int t = 0; t < 4; ++t) {
                    FU cc; cc.f = exp2f(sa[mt][t][r]);
                    QPs[prow][((t ^ (quad >> 1)) * 16) + lnx] = (ushort)(cc.u >> 16);
                }
            }
        }

        // O += P @ V ; l += P @ 1. pf unswizzle: phys = quad ^ ((ln>>2)&3)
        #pragma unroll
        for (int s = 0; s < 2; ++s) {
            const int pcol = s * 32 + ((quad ^ ((ln >> 2) & 3)) * 8);
            bf16x8 pf0 = *(const bf16x8*)(&QPs[pg * 64 + ww * 16 + ln][pcol]);
            bf16x8 pf1;
            if (doB) pf1 = *(const bf16x8*)(&QPs[pg * 64 + 32 + ww * 16 + ln][pcol]);
            #pragma unroll
            for (int t = 0; t < 4; ++t) {
                bf16x8 vf = *(const bf16x8*)(&Vs[t * 16 + ln][s * 32 + quad * 8]);
                acc_o[0][t] = __builtin_amdgcn_mfma_f32_16x16x32_bf16(pf0, vf, acc_o[0][t], 0, 0, 0);
                if (doB)
                    acc_o[1][t] = __builtin_amdgcn_mfma_f32_16x16x32_bf16(pf1, vf, acc_o[1][t], 0, 0, 0);
            }
            acc_l[0] = __builtin_amdgcn_mfma_f32_16x16x32_bf16(pf0, ones8, acc_l[0], 0, 0, 0);
            if (doB)
                acc_l[1] = __builtin_amdgcn_mfma_f32_16x16x32_bf16(pf1, ones8, acc_l[1], 0, 0, 0);
        }
    }

    // epilogue: normalize, write [B,S,H*64+dk]
    #pragma unroll
    for (int mt = 0; mt < 2; ++mt) {
        const int q0 = mt ? q0B : q0A;
        #pragma unroll
        for (int r = 0; r < 4; ++r) {
            float inv = 1.0f / acc_l[mt][r];
            int i = q0 + ww * 16 + quad * 4 + r;
            size_t rowoff = ((size_t)(b * SEQ + i)) * D_MODEL + hh * D_K;
            #pragma unroll
            for (int t = 0; t < 4; ++t)
                attn[rowoff + t * 16 + ln] = f2bf(acc_o[mt][t][r] * inv);
        }
    }
}

extern "C" void kernel_launch(void* const* d_in, const int* in_sizes, int n_in,
                              void* d_out, int out_size, void* d_ws, size_t ws_size,
                              hipStream_t stream)
{
    const void* x     = d_in[0];
    // d_in[1] = int32 tril mask -- causal handled analytically
    const void* w_qkv = d_in[2];
    const void* b_qkv = d_in[3];
    const void* w_out = d_in[4];
    const void* b_out = d_in[5];

    char* ws = (char*)d_ws;
    int*    flag   = (int*)ws;                  size_t off = 256;
    ushort* WqkvT  = (ushort*)(ws + off);       off += (size_t)3 * D_MODEL * D_MODEL * 2;
    ushort* WoutT  = (ushort*)(ws + off);       off += (size_t)D_MODEL * D_MODEL * 2;
    ushort* qkv_ws = (ushort*)(ws + off);       off += (size_t)BATCH * SEQ * 3 * D_MODEL * 2;
    ushort* xb     = (ushort*)(ws + off);       // aliases attn_ws: xb dead after QKV gemm
    ushort* attn_ws = xb;

    const int M = BATCH * SEQ;          // 4096

    prep_all<<<3072, 256, 0, stream>>>((const ushort*)x, w_qkv, w_out,
                                       xb, WqkvT, WoutT, flag);

    gemm128<1><<<dim3(3 * D_MODEL / 128, M / 128), 256, 0, stream>>>(
        x, xb, WqkvT, b_qkv, qkv_ws, 3 * D_MODEL, D_MODEL, flag);

    dim3 ga(BATCH * NUM_HEADS, 16);   // x = bh (XCD locality), y = ky
    flash_attn7<<<ga, 256, 0, stream>>>(qkv_ws, attn_ws);

    gemm128<0><<<dim3(D_MODEL / 128, M / 128), 256, 0, stream>>>(
        attn_ws, attn_ws, WoutT, b_out, d_out, D_MODEL, D_MODEL, flag);
}

// Round 13
// 217.963 us; speedup vs baseline: 1.1941x; 1.0410x over previous
//
#include <hip/hip_runtime.h>
#include <hip/hip_bf16.h>

#define D_MODEL 1024
#define NUM_HEADS 16
#define D_K 64
#define BATCH 2
#define SEQ 2048

typedef __attribute__((ext_vector_type(8))) short bf16x8;
typedef __attribute__((ext_vector_type(4))) float f32x4;

union P16 { int4 i4; ushort u[8]; };
union FU { float f; unsigned int u; };

__device__ __forceinline__ float bf2f(ushort u) {
    union { unsigned int i; float f; } c; c.i = ((unsigned int)u) << 16; return c.f;
}
__device__ __forceinline__ ushort f2bf(float f) {
    union { float f; unsigned int i; } c; c.f = f;
    unsigned int x = c.i;
    return (ushort)((x + 0x7fff + ((x >> 16) & 1)) >> 16);
}

// per-wave inline dtype detect (every wave reads the same 64 values -> uniform)
__device__ __forceinline__ bool wave_detect_f32(const ushort* x) {
    ushort u = x[2 * (threadIdx.x & 63)];
    int e = (u >> 7) & 0xFF;
    unsigned long long bl = __ballot(e >= 100 && e <= 141);
    return __popcll(bl) < 32;
}

// ---------------- fused prep: detect + convert_x + both weight transposes ----------------
__global__ __launch_bounds__(256)
void prep_all(const ushort* __restrict__ x, const void* __restrict__ Wq,
              const void* __restrict__ Wo, ushort* __restrict__ xb,
              ushort* __restrict__ WqT, ushort* __restrict__ WoT,
              int* __restrict__ flag)
{
    const bool f32 = wave_detect_f32(x);
    const int bx = blockIdx.x, tx = threadIdx.x;
    if (bx == 0 && tx == 0) flag[0] = f32 ? 1 : 0;

    if (bx >= 1024) {               // convert x -> bf16 (fp32 inputs only)
        if (!f32) return;
        int i = ((bx - 1024) * 256 + tx) * 8;
        const float* f = (const float*)x + i;
        float4 a = *(const float4*)f, b = *(const float4*)(f + 4);
        P16 r;
        r.u[0] = f2bf(a.x); r.u[1] = f2bf(a.y); r.u[2] = f2bf(a.z); r.u[3] = f2bf(a.w);
        r.u[4] = f2bf(b.x); r.u[5] = f2bf(b.y); r.u[6] = f2bf(b.z); r.u[7] = f2bf(b.w);
        *(int4*)(xb + i) = r.i4;
        return;
    }

    __shared__ ushort t[64][72];
    const int nb = bx & 63, kb = bx >> 6;
    const void* W; ushort* WT; int N, n0;
    if (nb < 48) { W = Wq; WT = WqT; N = 3 * D_MODEL; n0 = nb * 64; }
    else         { W = Wo; WT = WoT; N = D_MODEL;     n0 = (nb - 48) * 64; }
    const int k0 = kb * 64, K = D_MODEL;
    #pragma unroll
    for (int p = 0; p < 16; ++p) {
        int r = p * 4 + (tx >> 6), c = tx & 63;
        float v = f32 ? ((const float*)W)[(size_t)(k0 + r) * N + n0 + c]
                      : bf2f(((const ushort*)W)[(size_t)(k0 + r) * N + n0 + c]);
        t[r][c] = f2bf(v);
    }
    __syncthreads();
    #pragma unroll
    for (int p = 0; p < 16; ++p) {
        int nn = p * 4 + (tx >> 6), kk = tx & 63;
        WT[(size_t)(n0 + nn) * K + k0 + kk] = t[kk][nn];
    }
}

// ---------------- GEMM v2: register double-buffer K-loop ----------------
// Same 128x128 tile, same LDS image (XOR chunk swizzle), same frag reads and
// epilogue as the verified round-5 kernel. Only the staging path changed:
// gll16 (which forces a vmcnt(0) drain at the barrier every iter) is replaced
// by reg-prefetch: next tile's global loads issue after the barrier and their
// vmcnt wait lands before the NEXT iter's ds_write -- a full compute phase of
// slack (flash-v3-verified pattern).
// MODE 1: A = flag ? Aconv : Araw(bf16); out bf16 [row][N].
// MODE 0: A = Aconv; out dtype per flag, [row][N].
template<int MODE>
__global__ __launch_bounds__(256)
void gemm128(const void* __restrict__ Araw, const ushort* __restrict__ Aconv,
             const ushort* __restrict__ WT, const void* __restrict__ bias,
             void* __restrict__ out, int N, int K, const int* __restrict__ flag)
{
    __shared__ ushort As[128 * 32];
    __shared__ ushort Bs[128 * 32];

    const int f = *flag;
    const ushort* A = (MODE == 1) ? (f ? Aconv : (const ushort*)Araw) : Aconv;

    const int tid = threadIdx.x;
    const int w = tid >> 6, lane = tid & 63;
    const int ln = lane & 15, quad = lane >> 4;
    const int m0 = blockIdx.y * 128, n0 = blockIdx.x * 128;
    const int wm = (w >> 1) * 64, wn = (w & 1) * 64;

    // staging slots: s = w*128 + i*64 + lane; slot s -> LDS 16B chunk at s*8
    const int s0 = w * 128 + lane, s1 = s0 + 64;
    const int ar0 = s0 >> 2, ak0 = ((s0 & 3) ^ ((ar0 >> 1) & 3)) * 8;
    const int ar1 = s1 >> 2, ak1 = ((s1 & 3) ^ ((ar1 >> 1) & 3)) * 8;
    const size_t aoff0 = (size_t)(m0 + ar0) * K + ak0;
    const size_t aoff1 = (size_t)(m0 + ar1) * K + ak1;
    const size_t boff0 = (size_t)(n0 + ar0) * K + ak0;
    const size_t boff1 = (size_t)(n0 + ar1) * K + ak1;
    ushort* alds0 = As + s0 * 8;
    ushort* alds1 = As + s1 * 8;
    ushort* blds0 = Bs + s0 * 8;
    ushort* blds1 = Bs + s1 * 8;

    const int physc = (quad ^ ((ln >> 1) & 3)) * 8;

    f32x4 acc[4][4] = {};

    // preload k-tile 0
    int4 a0 = *(const int4*)(A + aoff0);
    int4 a1 = *(const int4*)(A + aoff1);
    int4 b0 = *(const int4*)(WT + boff0);
    int4 b1 = *(const int4*)(WT + boff1);

    for (int k0c = 0; k0c < K; k0c += 32) {
        __syncthreads();                 // prior iter's frag reads complete
        *(int4*)alds0 = a0;
        *(int4*)alds1 = a1;
        *(int4*)blds0 = b0;
        *(int4*)blds1 = b1;
        __syncthreads();                 // LDS visible block-wide

        if (k0c + 32 < K) {              // overlap next loads with compute
            a0 = *(const int4*)(A + aoff0 + k0c + 32);
            a1 = *(const int4*)(A + aoff1 + k0c + 32);
            b0 = *(const int4*)(WT + boff0 + k0c + 32);
            b1 = *(const int4*)(WT + boff1 + k0c + 32);
        }

        bf16x8 af[4], bf[4];
        #pragma unroll
        for (int t = 0; t < 4; ++t) {
            af[t] = *(const bf16x8*)(As + (wm + t * 16 + ln) * 32 + physc);
            bf[t] = *(const bf16x8*)(Bs + (wn + t * 16 + ln) * 32 + physc);
        }
        #pragma unroll
        for (int mi = 0; mi < 4; ++mi)
            #pragma unroll
            for (int ni = 0; ni < 4; ++ni)
                acc[mi][ni] = __builtin_amdgcn_mfma_f32_16x16x32_bf16(
                    af[mi], bf[ni], acc[mi][ni], 0, 0, 0);
    }

    #pragma unroll
    for (int mi = 0; mi < 4; ++mi) {
        #pragma unroll
        for (int ni = 0; ni < 4; ++ni) {
            int col = n0 + wn + ni * 16 + ln;
            float bb = f ? ((const float*)bias)[col] : bf2f(((const ushort*)bias)[col]);
            #pragma unroll
            for (int r = 0; r < 4; ++r) {
                int row = m0 + wm + mi * 16 + quad * 4 + r;
                float v = acc[mi][ni][r] + bb;
                if (MODE == 0 && f) ((float*)out)[(size_t)row * N + col] = v;
                else                ((ushort*)out)[(size_t)row * N + col] = f2bf(v);
            }
        }
    }
}

// ---------------- MFMA flash attention v7 (unchanged, verified round 12) ----------------
__global__ __launch_bounds__(256)
void flash_attn7(const ushort* __restrict__ qkv, ushort* __restrict__ attn)
{
    __shared__ ushort Ks[64][72];
    __shared__ ushort Vs[64][72];
    __shared__ ushort QPs[128][72];  // [pg*64 + mt*32 + local]

    const int tid  = threadIdx.x;          // 256 thr, 4 waves
    const int wave = tid >> 6, lane = tid & 63;
    const int ln   = lane & 15, quad = lane >> 4;
    const int pg   = wave >> 1, ww = wave & 1;
    const int bh   = blockIdx.x;    // all blocks of a bh land on XCD bh%8
    const int ky   = blockIdx.y;
    const int k    = (ky < 8) ? ky : 23 - ky;
    const int xx   = 2 * k + pg;
    const int b    = bh >> 4, hh = bh & (NUM_HEADS - 1);
    const int W3   = 3 * D_MODEL;
    const size_t hbase = (size_t)b * SEQ * W3 + hh * D_K;

    const int q0A = 32 * (63 - xx), q0B = 32 * xx;
    const int ntA = 32 - k, ntB = k + 1;     // identical for both pg

    const int qrr = tid >> 1, qcol = (tid & 1) * 32;       // Q: 128 rows x 64
    const int ksr = tid >> 2, ksc = (tid & 3) * 16;        // K: 64 rows, 2 int4
    const int vp  = tid & 31, vg = (tid >> 5) * 8;         // V: 8 b32 each

    // stage both pairs' Q tiles (128 rows), scaled by 0.125*log2(e)
    {
        const int qpg = qrr >> 6, qmt = (qrr >> 5) & 1, ql = qrr & 31;
        const int qxx = 2 * k + qpg;
        const int grow = qmt ? (32 * qxx + ql) : (32 * (63 - qxx) + ql);
        const ushort* src = qkv + hbase + (size_t)grow * W3 + qcol;
        #pragma unroll
        for (int h = 0; h < 4; ++h) {
            P16 v; v.i4 = *(const int4*)(src + h * 8);
            #pragma unroll
            for (int e = 0; e < 8; ++e) v.u[e] = f2bf(bf2f(v.u[e]) * 0.18033688011f);
            *(int4*)(&QPs[qrr][qcol + h * 8]) = v.i4;
        }
    }
    __syncthreads();
    bf16x8 qf[2][2];
    #pragma unroll
    for (int mt = 0; mt < 2; ++mt)
        #pragma unroll
        for (int s = 0; s < 2; ++s)
            qf[mt][s] = *(const bf16x8*)(&QPs[pg * 64 + mt * 32 + ww * 16 + ln][s * 32 + quad * 8]);

    f32x4 acc_o[2][4] = {};
    f32x4 acc_l[2] = {};

    bf16x8 ones8;
    #pragma unroll
    for (int e = 0; e < 8; ++e) ones8[e] = (short)0x3F80;   // bf16 1.0

    const ushort* Kbase = qkv + hbase + D_MODEL;
    const ushort* Vbase = qkv + hbase + 2 * D_MODEL;

    int4 kreg[2], vreg[2];
    {
        const ushort* ksrc = Kbase + (size_t)ksr * W3 + ksc;
        kreg[0] = *(const int4*)(ksrc);
        kreg[1] = *(const int4*)(ksrc + 8);
        vreg[0] = *(const int4*)(Vbase + (size_t)(2 * vp)     * W3 + vg);
        vreg[1] = *(const int4*)(Vbase + (size_t)(2 * vp + 1) * W3 + vg);
    }

    for (int jt = 0; jt < ntA; ++jt) {
        const int j0 = jt * 64;
        const bool doB = (jt < ntB);
        __syncthreads();

        *(int4*)(&Ks[ksr][ksc])     = kreg[0];
        *(int4*)(&Ks[ksr][ksc + 8]) = kreg[1];
        {
            P16 v0, v1; v0.i4 = vreg[0]; v1.i4 = vreg[1];
            #pragma unroll
            for (int e = 0; e < 8; ++e) {
                unsigned int pack = (unsigned int)v0.u[e] | ((unsigned int)v1.u[e] << 16);
                *(unsigned int*)(&Vs[vg + e][2 * vp]) = pack;
            }
        }
        __syncthreads();

        if (jt + 1 < ntA) {
            const int jn = j0 + 64;
            const ushort* ksrc = Kbase + (size_t)(jn + ksr) * W3 + ksc;
            kreg[0] = *(const int4*)(ksrc);
            kreg[1] = *(const int4*)(ksrc + 8);
            vreg[0] = *(const int4*)(Vbase + (size_t)(jn + 2 * vp)     * W3 + vg);
            vreg[1] = *(const int4*)(Vbase + (size_t)(jn + 2 * vp + 1) * W3 + vg);
        }

        f32x4 sa[2][4];
        #pragma unroll
        for (int t = 0; t < 4; ++t) {
            bf16x8 k0 = *(const bf16x8*)(&Ks[t * 16 + ln][quad * 8]);
            bf16x8 k1 = *(const bf16x8*)(&Ks[t * 16 + ln][32 + quad * 8]);
            {
                f32x4 z = {};
                z = __builtin_amdgcn_mfma_f32_16x16x32_bf16(qf[0][0], k0, z, 0, 0, 0);
                z = __builtin_amdgcn_mfma_f32_16x16x32_bf16(qf[0][1], k1, z, 0, 0, 0);
                sa[0][t] = z;
            }
            if (doB) {
                f32x4 z = {};
                z = __builtin_amdgcn_mfma_f32_16x16x32_bf16(qf[1][0], k0, z, 0, 0, 0);
                z = __builtin_amdgcn_mfma_f32_16x16x32_bf16(qf[1][1], k1, z, 0, 0, 0);
                sa[1][t] = z;
            }
        }

        if (jt == ntA - 1) {
            const int rowb = q0A + ww * 16 + quad * 4;
            #pragma unroll
            for (int t = 0; t < 4; ++t)
                #pragma unroll
                for (int r = 0; r < 4; ++r)
                    if (j0 + t * 16 + ln > rowb + r) sa[0][t][r] = -1e30f;
        }
        if (doB && jt == ntB - 1) {
            const int rowb = q0B + ww * 16 + quad * 4;
            #pragma unroll
            for (int t = 0; t < 4; ++t)
                #pragma unroll
                for (int r = 0; r < 4; ++r)
                    if (j0 + t * 16 + ln > rowb + r) sa[1][t][r] = -1e30f;
        }

        const int lnx = ln ^ ((quad & 1) * 8);
        #pragma unroll
        for (int mt = 0; mt < 2; ++mt) {
            if (mt && !doB) break;
            #pragma unroll
            for (int r = 0; r < 4; ++r) {
                const int prow = pg * 64 + mt * 32 + ww * 16 + quad * 4 + r;
                #pragma unroll
                for (int t = 0; t < 4; ++t) {
                    FU cc; cc.f = exp2f(sa[mt][t][r]);
                    QPs[prow][((t ^ (quad >> 1)) * 16) + lnx] = (ushort)(cc.u >> 16);
                }
            }
        }

        #pragma unroll
        for (int s = 0; s < 2; ++s) {
            const int pcol = s * 32 + ((quad ^ ((ln >> 2) & 3)) * 8);
            bf16x8 pf0 = *(const bf16x8*)(&QPs[pg * 64 + ww * 16 + ln][pcol]);
            bf16x8 pf1;
            if (doB) pf1 = *(const bf16x8*)(&QPs[pg * 64 + 32 + ww * 16 + ln][pcol]);
            #pragma unroll
            for (int t = 0; t < 4; ++t) {
                bf16x8 vf = *(const bf16x8*)(&Vs[t * 16 + ln][s * 32 + quad * 8]);
                acc_o[0][t] = __builtin_amdgcn_mfma_f32_16x16x32_bf16(pf0, vf, acc_o[0][t], 0, 0, 0);
                if (doB)
                    acc_o[1][t] = __builtin_amdgcn_mfma_f32_16x16x32_bf16(pf1, vf, acc_o[1][t], 0, 0, 0);
            }
            acc_l[0] = __builtin_amdgcn_mfma_f32_16x16x32_bf16(pf0, ones8, acc_l[0], 0, 0, 0);
            if (doB)
                acc_l[1] = __builtin_amdgcn_mfma_f32_16x16x32_bf16(pf1, ones8, acc_l[1], 0, 0, 0);
        }
    }

    #pragma unroll
    for (int mt = 0; mt < 2; ++mt) {
        const int q0 = mt ? q0B : q0A;
        #pragma unroll
        for (int r = 0; r < 4; ++r) {
            float inv = 1.0f / acc_l[mt][r];
            int i = q0 + ww * 16 + quad * 4 + r;
            size_t rowoff = ((size_t)(b * SEQ + i)) * D_MODEL + hh * D_K;
            #pragma unroll
            for (int t = 0; t < 4; ++t)
                attn[rowoff + t * 16 + ln] = f2bf(acc_o[mt][t][r] * inv);
        }
    }
}

extern "C" void kernel_launch(void* const* d_in, const int* in_sizes, int n_in,
                              void* d_out, int out_size, void* d_ws, size_t ws_size,
                              hipStream_t stream)
{
    const void* x     = d_in[0];
    // d_in[1] = int32 tril mask -- causal handled analytically
    const void* w_qkv = d_in[2];
    const void* b_qkv = d_in[3];
    const void* w_out = d_in[4];
    const void* b_out = d_in[5];

    char* ws = (char*)d_ws;
    int*    flag   = (int*)ws;                  size_t off = 256;
    ushort* WqkvT  = (ushort*)(ws + off);       off += (size_t)3 * D_MODEL * D_MODEL * 2;
    ushort* WoutT  = (ushort*)(ws + off);       off += (size_t)D_MODEL * D_MODEL * 2;
    ushort* qkv_ws = (ushort*)(ws + off);       off += (size_t)BATCH * SEQ * 3 * D_MODEL * 2;
    ushort* xb     = (ushort*)(ws + off);       // aliases attn_ws: xb dead after QKV gemm
    ushort* attn_ws = xb;

    const int M = BATCH * SEQ;          // 4096

    prep_all<<<3072, 256, 0, stream>>>((const ushort*)x, w_qkv, w_out,
                                       xb, WqkvT, WoutT, flag);

    gemm128<1><<<dim3(3 * D_MODEL / 128, M / 128), 256, 0, stream>>>(
        x, xb, WqkvT, b_qkv, qkv_ws, 3 * D_MODEL, D_MODEL, flag);

    dim3 ga(BATCH * NUM_HEADS, 16);   // x = bh (XCD locality), y = ky
    flash_attn7<<<ga, 256, 0, stream>>>(qkv_ws, attn_ws);

    gemm128<0><<<dim3(D_MODEL / 128, M / 128), 256, 0, stream>>>(
        attn_ws, attn_ws, WoutT, b_out, d_out, D_MODEL, D_MODEL, flag);
}